// Round 1
// 165.058 us; speedup vs baseline: 1.0172x; 1.0172x over previous
//
#include <hip/hip_runtime.h>

// out[b, c, w, f] = X[b, c, f*HOP + w]
// B=16, C=2, T=262144, WINDOW=1024, HOP=256, NF=1021
#define WINDOW_SZ 1024
#define HOP_SZ    256
#define NFRAMES   1021
#define T_LEN     262144

#define FT 64            // frames per tile
#define WT 64            // window positions per tile
#define S  68            // LDS row stride in floats: 272B rows -> 16B aligned, quad-access conflict-free

// 16B-aligned vec4 (LDS) and 4B-aligned vec4 (global stores: 1021-stride rows are only dword-aligned)
typedef float f4a __attribute__((ext_vector_type(4)));
typedef float f4u __attribute__((ext_vector_type(4), aligned(4)));

__global__ __launch_bounds__(256)
void frame_transpose_kernel(const float* __restrict__ X,
                            float* __restrict__ out) {
    __shared__ float lds[WT * S];   // lds[w][f], f contiguous, 17.4 KB

    // Chunked XCD swizzle: 8192 blocks, dispatch round-robins id%8 across XCDs.
    // work = xcd*1024 + idx  ->  each XCD owns 4 complete bc slabs (1 MiB input
    // each, L2-resident), so frame-overlap re-reads AND f-tile boundary lines
    // stay on one XCD's L2.
    const int bid  = blockIdx.x;
    const int work = ((bid & 7) << 10) | (bid >> 3);
    const int xt   = work & 15;          // f-tile (fastest)
    const int yt   = (work >> 4) & 15;   // w-tile
    const int bc   = work >> 8;          // 0..31

    const int tid = threadIdx.x;
    const int f0  = xt * FT;
    const int w0  = yt * WT;

    const float* Xbc = X + (size_t)bc * T_LEN;

    const int j = tid & 15;   // w-quad index  (w = 4j..4j+3)
    const int g = tid >> 4;   // f-quad index  (f = 4g..4g+3)

    // ---- load phase: 4x float4 along w at 4 consecutive frames, register
    //      transpose, 4x ds_write_b128 into f-contiguous rows ----
    {
        const float* src = Xbc + (size_t)(f0 + 4 * g) * HOP_SZ + w0 + 4 * j;
        float4 v0, v1, v2, v3;
        if (f0 + 4 * g + 3 < NFRAMES) {           // fast path: all 15 full tiles + most of tail
            v0 = *(const float4*)(src);
            v1 = *(const float4*)(src + HOP_SZ);
            v2 = *(const float4*)(src + 2 * HOP_SZ);
            v3 = *(const float4*)(src + 3 * HOP_SZ);
        } else {                                   // tail quad of last f-tile (f=1020 only)
            v0 = v1 = v2 = v3 = float4{0.f, 0.f, 0.f, 0.f};
            if (f0 + 4 * g + 0 < NFRAMES) v0 = *(const float4*)(src);
            if (f0 + 4 * g + 1 < NFRAMES) v1 = *(const float4*)(src + HOP_SZ);
            if (f0 + 4 * g + 2 < NFRAMES) v2 = *(const float4*)(src + 2 * HOP_SZ);
        }
        // rows 4j..4j+3, columns 4g..4g+3; bank-start (16(j&1)+4k+4(g&7))&31
        // covers all eight 4-bank windows uniformly -> inherent-only (free)
        float* row = &lds[(4 * j) * S + 4 * g];
        *(f4a*)(row        ) = f4a{v0.x, v1.x, v2.x, v3.x};
        *(f4a*)(row + S    ) = f4a{v0.y, v1.y, v2.y, v3.y};
        *(f4a*)(row + 2 * S) = f4a{v0.z, v1.z, v2.z, v3.z};
        *(f4a*)(row + 3 * S) = f4a{v0.w, v1.w, v2.w, v3.w};
    }

    __syncthreads();

    // ---- store phase: 4x ds_read_b128 + 4x global_store_dwordx4 per thread
    //      (1 KiB contiguous-per-row per wave-store) ----
    {
        const int q  = tid & 15;   // f-quad
        const int wl = tid >> 4;   // row base (0..15), +16 per pass
        const int fq = f0 + 4 * q;
        float* obase = out + ((size_t)bc * WINDOW_SZ + (w0 + wl)) * (size_t)NFRAMES + fq;
        if (fq + 3 < NFRAMES) {
#pragma unroll
            for (int r = 0; r < 4; ++r) {
                f4a t = *(const f4a*)&lds[(wl + 16 * r) * S + 4 * q];
                *(f4u*)(obase + (size_t)(16 * r) * NFRAMES) = (f4u)t;
            }
        } else if (fq < NFRAMES) {
            // last quad of last f-tile: only f=1020 valid -> scalar
#pragma unroll
            for (int r = 0; r < 4; ++r) {
                obase[(size_t)(16 * r) * NFRAMES] = lds[(wl + 16 * r) * S + 4 * q];
            }
        }
    }
}

extern "C" void kernel_launch(void* const* d_in, const int* in_sizes, int n_in,
                              void* d_out, int out_size, void* d_ws, size_t ws_size,
                              hipStream_t stream) {
    const float* X = (const float*)d_in[0];
    float* out = (float*)d_out;

    dim3 block(256, 1, 1);
    dim3 grid(16 * 16 * 32, 1, 1);   // flattened; swizzled in-kernel
    frame_transpose_kernel<<<grid, block, 0, stream>>>(X, out);
}